// Round 1
// baseline (29328.568 us; speedup 1.0000x reference)
//
#include <hip/hip_runtime.h>
#include <hip/hip_bf16.h>

// LSTM decoder: B=256, T=512, H=1024, O=1
// Per step t: gates = x_t * w_in + h @ W_hh^T + (b_ih+b_hh)
//             i,f,g,o = split(gates); c = sig(f)*c + sig(i)*tanh(g); h = sig(o)*tanh(c)
// Output: h_T @ W_fc^T + b_fc  (256 floats)
//
// Strategy v1 (fp32 baseline): one kernel launch per timestep (512 graph nodes).
// Each WG owns a 32-batch x 32-hcol tile -> computes the 32x128 gate tile
// (i/f/g/o quadruple for its 32 h-columns) and the c/h update locally.
// No intra-step inter-WG dependency; cross-step via double-buffered h in ws.

#define BB 256
#define TT 512
#define HH 1024

#define BM 32   // batch rows per WG
#define BJ 32   // h-cols per WG -> 4*BJ = 128 W_hh rows
#define BK 32   // K-tile

__device__ __forceinline__ float sigf(float x) {
    return 1.0f / (1.0f + __expf(-x));
}
__device__ __forceinline__ float tanhf_fast(float x) {
    // 1 - 2/(e^{2x}+1); saturates correctly at +/-1 for large |x|
    return 1.0f - 2.0f / (__expf(2.0f * x) + 1.0f);
}

__global__ void prep_kernel(const float* __restrict__ h0, const float* __restrict__ c0,
                            float* __restrict__ hbuf, float* __restrict__ cbuf) {
    int i = blockIdx.x * blockDim.x + threadIdx.x;
    if (i < BB * HH) {
        hbuf[i] = h0[i];
        cbuf[i] = c0[i];
    }
}

__global__ __launch_bounds__(256) void lstm_step(
    const float* __restrict__ y_hist,  // (B, T)
    const float* __restrict__ w_in,    // (4H)  [= W_ih[:,0]]
    const float* __restrict__ W_hh,    // (4H, H) row-major
    const float* __restrict__ b_ih,    // (4H)
    const float* __restrict__ b_hh,    // (4H)
    const float* __restrict__ h_src,   // (B, H)
    float* __restrict__ h_dst,         // (B, H)
    float* __restrict__ c_buf,         // (B, H) in-place
    int t)
{
    // LDS tiles in [k][element] layout: inner-loop reads are float4, conflict-free
    __shared__ __align__(16) float hs[BK][BM + 4];        // [k][m]  row=36 floats (16B-aligned rows)
    __shared__ __align__(16) float wsm[BK][4 * BJ + 4];   // [k][r]  row=132 floats, r = gate*32 + jl
    __shared__ __align__(16) float Gs[BM][4 * BJ + 4];    // [m][r]  gate staging for epilogue regroup

    const int tid = threadIdx.x;
    const int tx = tid & 31;   // 0..31
    const int ty = tid >> 5;   // 0..7
    const int row0 = blockIdx.x * BM;   // batch tile base
    const int j0 = blockIdx.y * BJ;     // h-col tile base

    float acc[4][4] = {};  // thread tile: m = ty*4+mm, n(r) = tx*4+nn

    for (int k0 = 0; k0 < HH; k0 += BK) {
        // stage h tile: hs[k][m], k=tx (coalesced global), m=ty+8i
#pragma unroll
        for (int i = 0; i < 4; ++i) {
            int m = ty + 8 * i;
            hs[tx][m] = h_src[(row0 + m) * HH + k0 + tx];
        }
        // stage W tile: wsm[k][r], r = gate*32 + jl -> W_hh row = gate*1024 + j0 + jl
#pragma unroll
        for (int i = 0; i < 16; ++i) {
            int r = ty + 8 * i;
            int wrow = ((r >> 5) << 10) + j0 + (r & 31);
            wsm[tx][r] = W_hh[wrow * HH + k0 + tx];
        }
        __syncthreads();
#pragma unroll
        for (int k = 0; k < BK; ++k) {
            float4 a = *reinterpret_cast<const float4*>(&hs[k][ty * 4]);
            float4 b = *reinterpret_cast<const float4*>(&wsm[k][tx * 4]);
            acc[0][0] = fmaf(a.x, b.x, acc[0][0]);
            acc[0][1] = fmaf(a.x, b.y, acc[0][1]);
            acc[0][2] = fmaf(a.x, b.z, acc[0][2]);
            acc[0][3] = fmaf(a.x, b.w, acc[0][3]);
            acc[1][0] = fmaf(a.y, b.x, acc[1][0]);
            acc[1][1] = fmaf(a.y, b.y, acc[1][1]);
            acc[1][2] = fmaf(a.y, b.z, acc[1][2]);
            acc[1][3] = fmaf(a.y, b.w, acc[1][3]);
            acc[2][0] = fmaf(a.z, b.x, acc[2][0]);
            acc[2][1] = fmaf(a.z, b.y, acc[2][1]);
            acc[2][2] = fmaf(a.z, b.z, acc[2][2]);
            acc[2][3] = fmaf(a.z, b.w, acc[2][3]);
            acc[3][0] = fmaf(a.w, b.x, acc[3][0]);
            acc[3][1] = fmaf(a.w, b.y, acc[3][1]);
            acc[3][2] = fmaf(a.w, b.z, acc[3][2]);
            acc[3][3] = fmaf(a.w, b.w, acc[3][3]);
        }
        __syncthreads();
    }

    // stage gate tile to LDS so each thread can regroup i/f/g/o at the same j
#pragma unroll
    for (int mm = 0; mm < 4; ++mm) {
        *reinterpret_cast<float4*>(&Gs[ty * 4 + mm][tx * 4]) =
            make_float4(acc[mm][0], acc[mm][1], acc[mm][2], acc[mm][3]);
    }
    __syncthreads();

    // epilogue: thread owns column j = j0+tx, rows m = ty+8i
    const int j = j0 + tx;
    const float wi_i = w_in[j];
    const float wi_f = w_in[HH + j];
    const float wi_g = w_in[2 * HH + j];
    const float wi_o = w_in[3 * HH + j];
    const float bi_i = b_ih[j] + b_hh[j];
    const float bi_f = b_ih[HH + j] + b_hh[HH + j];
    const float bi_g = b_ih[2 * HH + j] + b_hh[2 * HH + j];
    const float bi_o = b_ih[3 * HH + j] + b_hh[3 * HH + j];

#pragma unroll
    for (int i = 0; i < 4; ++i) {
        int m = ty + 8 * i;
        int b = row0 + m;
        float x = y_hist[b * TT + t];
        float gi = Gs[m][tx]           + x * wi_i + bi_i;
        float gf = Gs[m][BJ + tx]      + x * wi_f + bi_f;
        float gg = Gs[m][2 * BJ + tx]  + x * wi_g + bi_g;
        float go = Gs[m][3 * BJ + tx]  + x * wi_o + bi_o;
        float co = c_buf[b * HH + j];
        float cn = sigf(gf) * co + sigf(gi) * tanhf_fast(gg);
        float hn = sigf(go) * tanhf_fast(cn);
        c_buf[b * HH + j] = cn;
        h_dst[b * HH + j] = hn;
    }
}

__global__ __launch_bounds__(256) void fc_kernel(
    const float* __restrict__ h,      // (B, H) final hidden
    const float* __restrict__ W_fc,   // (1, H)
    const float* __restrict__ b_fc,   // (1)
    float* __restrict__ out)          // (B)
{
    int b = blockIdx.x;
    int tid = threadIdx.x;
    float s = 0.0f;
    for (int k = tid; k < HH; k += 256)
        s = fmaf(h[b * HH + k], W_fc[k], s);
    __shared__ float red[256];
    red[tid] = s;
    __syncthreads();
    for (int off = 128; off > 0; off >>= 1) {
        if (tid < off) red[tid] += red[tid + off];
        __syncthreads();
    }
    if (tid == 0) out[b] = red[0] + b_fc[0];
}

extern "C" void kernel_launch(void* const* d_in, const int* in_sizes, int n_in,
                              void* d_out, int out_size, void* d_ws, size_t ws_size,
                              hipStream_t stream) {
    const float* y_hist = (const float*)d_in[0];  // (256, 512)
    const float* W_ih   = (const float*)d_in[1];  // (4096, 1) -> w_in flat
    const float* W_hh   = (const float*)d_in[2];  // (4096, 1024)
    const float* b_ih   = (const float*)d_in[3];  // (4096)
    const float* b_hh   = (const float*)d_in[4];  // (4096)
    const float* W_fc   = (const float*)d_in[5];  // (1, 1024)
    const float* b_fc   = (const float*)d_in[6];  // (1)
    const float* h0     = (const float*)d_in[7];  // (256, 1024)
    const float* c0     = (const float*)d_in[8];  // (256, 1024)
    float* out = (float*)d_out;

    float* ws = (float*)d_ws;
    float* hbuf0 = ws;                 // 256*1024 floats
    float* hbuf1 = ws + BB * HH;       // 256*1024 floats
    float* cbuf  = ws + 2 * BB * HH;   // 256*1024 floats

    prep_kernel<<<(BB * HH + 255) / 256, 256, 0, stream>>>(h0, c0, hbuf0, cbuf);

    dim3 grid(BB / BM, HH / BJ);  // (8, 32) = 256 WGs, 1 per CU
    for (int t = 0; t < TT; ++t) {
        const float* hs = (t & 1) ? hbuf1 : hbuf0;
        float* hd       = (t & 1) ? hbuf0 : hbuf1;
        lstm_step<<<grid, 256, 0, stream>>>(y_hist, W_ih, W_hh, b_ih, b_hh,
                                            hs, hd, cbuf, t);
    }
    // T=512 even: final h lands in hbuf0
    fc_kernel<<<BB, 256, 0, stream>>>(hbuf0, W_fc, b_fc, out);
}

// Round 2
// 8909.249 us; speedup vs baseline: 3.2919x; 3.2919x over previous
//
#include <hip/hip_runtime.h>
#include <hip/hip_bf16.h>

// LSTM decoder B=256, T=512, H=1024. Split-bf16 MFMA GEMM per step.
// gates = h @ W_hh^T + x*w_in + bias, computed as
//   A_hi*W_hi + A_hi*W_lo + A_lo*W_hi  (bf16 MFMA, fp32 accum, err ~2^-16)
// Per-WG tile: M=64 batch rows x N=64 gate cols (16 j x 4 gates).
// W_hh pre-packed into MFMA fragment order (coalesced 1KB wave loads).
// h stored as bf16 hi/lo pair, staged via double-buffered fragment-packed LDS.

#define BB 256
#define TT 512
#define HH 1024

typedef __attribute__((ext_vector_type(8))) short short8;
typedef __attribute__((ext_vector_type(4))) float float4v;

#define MFMA(a, b, c) __builtin_amdgcn_mfma_f32_16x16x32_bf16((a), (b), (c), 0, 0, 0)

#define WP_CPOFF ((size_t)4194304)       // shorts per W copy: 64jt*4g*32ks*64lane*8
#define HBUF_ELEMS ((size_t)BB * HH)     // 262144

__device__ __forceinline__ float sigf(float x) { return 1.0f / (1.0f + __expf(-x)); }
__device__ __forceinline__ float tanhf_fast(float x) {
    return 1.0f - 2.0f / (__expf(2.0f * x) + 1.0f);
}
__device__ __forceinline__ unsigned short f2bf_u(float x) {
    __hip_bfloat16 b = __float2bfloat16(x);
    return __builtin_bit_cast(unsigned short, b);
}
__device__ __forceinline__ float bfu2f(unsigned short u) {
    __hip_bfloat16 b = __builtin_bit_cast(__hip_bfloat16, u);
    return __bfloat162float(b);
}

// ---- prep: pack W_hh (4096x1024 f32) into fragment-ordered bf16 hi/lo ----
// Wp[cp][jt(64)][g(4)][ks(32)][lane(64)][8]
__global__ __launch_bounds__(256) void pack_w(const float* __restrict__ W_hh,
                                              unsigned short* __restrict__ Wp) {
    int gid = blockIdx.x * 256 + threadIdx.x;   // 0..524287
    int lane = gid & 63;
    int ks = (gid >> 6) & 31;
    int g = (gid >> 11) & 3;
    int jt = (gid >> 13) & 63;
    int r = g * HH + jt * 16 + (lane & 15);
    int k = ks * 32 + (lane >> 4) * 8;
    const float* src = W_hh + (size_t)r * HH + k;
    size_t base = ((((size_t)jt * 4 + g) * 32 + ks) * 64 + lane) * 8;
#pragma unroll
    for (int e = 0; e < 8; ++e) {
        float v = src[e];
        unsigned short hi = f2bf_u(v);
        Wp[base + e] = hi;
        Wp[WP_CPOFF + base + e] = f2bf_u(v - bfu2f(hi));
    }
}

// ---- prep: h0 -> bf16 hi/lo, c0 -> c_buf ----
__global__ __launch_bounds__(256) void prep_state(const float* __restrict__ h0,
                                                  const float* __restrict__ c0,
                                                  unsigned short* __restrict__ hbuf,
                                                  float* __restrict__ cbuf) {
    int i = blockIdx.x * 256 + threadIdx.x;
    if (i < BB * HH) {
        float v = h0[i];
        unsigned short hi = f2bf_u(v);
        hbuf[i] = hi;
        hbuf[HBUF_ELEMS + i] = f2bf_u(v - bfu2f(hi));
        cbuf[i] = c0[i];
    }
}

// ---- one LSTM timestep ----
__global__ __launch_bounds__(256, 1) void lstm_step(
    const float* __restrict__ y_hist,
    const float* __restrict__ W_ih,           // (4096) flat
    const float* __restrict__ b_ih,
    const float* __restrict__ b_hh,
    const unsigned short* __restrict__ Wp,    // packed bf16 hi/lo
    const unsigned short* __restrict__ h_src, // [2][B*H] hi,lo
    unsigned short* __restrict__ h_dst,       // [2][B*H]
    float* __restrict__ c_buf,                // [B*H] f32, in-place
    int t)
{
    // Af: fragment-packed A chunk, double buffered.
    // slot layout: ((cp*4+mt)*2+ksl)*64 + slot, 8 bf16 per slot (16B), conflict-free
    __shared__ unsigned short Af[2][8192];    // 2 x 16KB
    __shared__ float Gs[64][80];              // gate staging, stride 80 -> 2-way only

    const int tid = threadIdx.x;
    const int lane = tid & 63;
    const int wv = tid >> 6;                  // wave id == gate id (0..3)
    const int bid = blockIdx.x;
    // XCD swizzle: bid%8 == jt/8 -> each XCD's 32 WGs share 8 jt slices (2MB W in its L2)
    const int jt = ((bid & 7) << 3) | ((bid >> 3) & 7);   // 0..63
    const int m0 = (bid >> 6) << 6;                        // 0,64,128,192

    // --- A staging mapping: thread loads row ar, cols [ac, ac+16) of the 64x64 chunk
    const int ar = tid >> 2;                  // 0..63
    const int ac = (tid & 3) << 4;            // 0,16,32,48
    const unsigned short* gsrc0 = h_src + (size_t)(m0 + ar) * HH + ac;
    int ldsoff[2][2];                         // [cp][q] in 16B units
#pragma unroll
    for (int cp = 0; cp < 2; ++cp)
#pragma unroll
        for (int q = 0; q < 2; ++q) {
            int c8 = ac + q * 8;
            int mt = ar >> 4;
            int ksl = c8 >> 5;
            int slot = (ar & 15) + (((c8 & 31) >> 3) << 4);
            ldsoff[cp][q] = (((cp * 4 + mt) * 2 + ksl) * 64 + slot);
        }

    const unsigned short* WpW = Wp + (((size_t)jt * 4 + wv) * 32) * 512;

    float4v acc[4] = {{0.f, 0.f, 0.f, 0.f}, {0.f, 0.f, 0.f, 0.f},
                      {0.f, 0.f, 0.f, 0.f}, {0.f, 0.f, 0.f, 0.f}};

    short8 pa[2][2];
    short8 wc[2][2], wn[2][2];

    // prologue: chunk 0
#pragma unroll
    for (int cp = 0; cp < 2; ++cp)
#pragma unroll
        for (int q = 0; q < 2; ++q)
            pa[cp][q] = *(const short8*)(gsrc0 + (size_t)cp * HBUF_ELEMS + q * 8);
#pragma unroll
    for (int ksl = 0; ksl < 2; ++ksl)
#pragma unroll
        for (int cp = 0; cp < 2; ++cp)
            wc[ksl][cp] = *(const short8*)(WpW + (size_t)cp * WP_CPOFF + ksl * 512 + lane * 8);
#pragma unroll
    for (int cp = 0; cp < 2; ++cp)
#pragma unroll
        for (int q = 0; q < 2; ++q)
            *(short8*)&Af[0][ldsoff[cp][q] * 8] = pa[cp][q];
    __syncthreads();

    for (int ch = 0; ch < 16; ++ch) {
        const int cur = ch & 1;
        if (ch < 15) {
            const int k0 = (ch + 1) * 64;
#pragma unroll
            for (int cp = 0; cp < 2; ++cp)
#pragma unroll
                for (int q = 0; q < 2; ++q)
                    pa[cp][q] = *(const short8*)(gsrc0 + (size_t)cp * HBUF_ELEMS + k0 + q * 8);
#pragma unroll
            for (int ksl = 0; ksl < 2; ++ksl)
#pragma unroll
                for (int cp = 0; cp < 2; ++cp)
                    wn[ksl][cp] = *(const short8*)(WpW + (size_t)cp * WP_CPOFF +
                                                   ((ch + 1) * 2 + ksl) * 512 + lane * 8);
        }
#pragma unroll
        for (int ksl = 0; ksl < 2; ++ksl) {
            short8 ah[4], al[4];
#pragma unroll
            for (int mt = 0; mt < 4; ++mt) {
                ah[mt] = *(const short8*)&Af[cur][(((0 * 4 + mt) * 2 + ksl) * 64 + lane) * 8];
                al[mt] = *(const short8*)&Af[cur][(((1 * 4 + mt) * 2 + ksl) * 64 + lane) * 8];
            }
#pragma unroll
            for (int mt = 0; mt < 4; ++mt) {
                acc[mt] = MFMA(al[mt], wc[ksl][0], acc[mt]);   // A_lo * W_hi
                acc[mt] = MFMA(ah[mt], wc[ksl][1], acc[mt]);   // A_hi * W_lo
                acc[mt] = MFMA(ah[mt], wc[ksl][0], acc[mt]);   // A_hi * W_hi
            }
        }
        if (ch < 15) {
#pragma unroll
            for (int cp = 0; cp < 2; ++cp)
#pragma unroll
                for (int q = 0; q < 2; ++q)
                    *(short8*)&Af[1 - cur][ldsoff[cp][q] * 8] = pa[cp][q];
            __syncthreads();
#pragma unroll
            for (int ksl = 0; ksl < 2; ++ksl)
#pragma unroll
                for (int cp = 0; cp < 2; ++cp)
                    wc[ksl][cp] = wn[ksl][cp];
        }
    }

    // --- epilogue: stage gates to LDS, regroup i/f/g/o per (m, j)
    // C/D layout: col = lane&15 (n), row = (lane>>4)*4 + reg (m)
#pragma unroll
    for (int mt = 0; mt < 4; ++mt)
#pragma unroll
        for (int r = 0; r < 4; ++r)
            Gs[mt * 16 + (lane >> 4) * 4 + r][wv * 16 + (lane & 15)] = acc[mt][r];
    __syncthreads();

    const int jl = tid & 15;
    const int mb = tid >> 4;                  // 0..15
    const int j = jt * 16 + jl;
    float wi[4], bsum[4];
#pragma unroll
    for (int g = 0; g < 4; ++g) {
        wi[g] = W_ih[g * HH + j];
        bsum[g] = b_ih[g * HH + j] + b_hh[g * HH + j];
    }
#pragma unroll
    for (int i = 0; i < 4; ++i) {
        int m = mb + 16 * i;
        int b = m0 + m;
        float x = y_hist[(size_t)b * TT + t];
        float gi = Gs[m][jl] + x * wi[0] + bsum[0];
        float gf = Gs[m][16 + jl] + x * wi[1] + bsum[1];
        float gg = Gs[m][32 + jl] + x * wi[2] + bsum[2];
        float go = Gs[m][48 + jl] + x * wi[3] + bsum[3];
        float c_old = c_buf[(size_t)b * HH + j];
        float cn = sigf(gf) * c_old + sigf(gi) * tanhf_fast(gg);
        float hn = sigf(go) * tanhf_fast(cn);
        c_buf[(size_t)b * HH + j] = cn;
        unsigned short hi_ = f2bf_u(hn);
        h_dst[(size_t)b * HH + j] = hi_;
        h_dst[HBUF_ELEMS + (size_t)b * HH + j] = f2bf_u(hn - bfu2f(hi_));
    }
}

// ---- final FC: out[b] = sum_k (h_hi+h_lo)[b][k] * W_fc[k] + b_fc ----
__global__ __launch_bounds__(256) void fc_kernel(
    const unsigned short* __restrict__ h,     // [2][B*H]
    const float* __restrict__ W_fc,
    const float* __restrict__ b_fc,
    float* __restrict__ out)
{
    int b = blockIdx.x;
    int tid = threadIdx.x;
    float s = 0.0f;
    for (int k = tid; k < HH; k += 256) {
        float hv = bfu2f(h[(size_t)b * HH + k]) + bfu2f(h[HBUF_ELEMS + (size_t)b * HH + k]);
        s = fmaf(hv, W_fc[k], s);
    }
    __shared__ float red[256];
    red[tid] = s;
    __syncthreads();
    for (int off = 128; off > 0; off >>= 1) {
        if (tid < off) red[tid] += red[tid + off];
        __syncthreads();
    }
    if (tid == 0) out[b] = red[0] + b_fc[0];
}

extern "C" void kernel_launch(void* const* d_in, const int* in_sizes, int n_in,
                              void* d_out, int out_size, void* d_ws, size_t ws_size,
                              hipStream_t stream) {
    const float* y_hist = (const float*)d_in[0];
    const float* W_ih   = (const float*)d_in[1];
    const float* W_hh   = (const float*)d_in[2];
    const float* b_ih   = (const float*)d_in[3];
    const float* b_hh   = (const float*)d_in[4];
    const float* W_fc   = (const float*)d_in[5];
    const float* b_fc   = (const float*)d_in[6];
    const float* h0     = (const float*)d_in[7];
    const float* c0     = (const float*)d_in[8];
    float* out = (float*)d_out;

    // ws layout: Wp (16MB bf16 hi/lo) | hbuf0 (1MB) | hbuf1 (1MB) | c_buf (1MB f32)
    unsigned short* Wp = (unsigned short*)d_ws;
    unsigned short* hb0 = Wp + 2 * WP_CPOFF;          // 8388608 shorts
    unsigned short* hb1 = hb0 + 2 * HBUF_ELEMS;
    float* cbuf = (float*)(hb1 + 2 * HBUF_ELEMS);

    pack_w<<<2048, 256, 0, stream>>>(W_hh, Wp);
    prep_state<<<(BB * HH + 255) / 256, 256, 0, stream>>>(h0, c0, hb0, cbuf);

    for (int t = 0; t < TT; ++t) {
        const unsigned short* hs = (t & 1) ? hb1 : hb0;
        unsigned short* hd       = (t & 1) ? hb0 : hb1;
        lstm_step<<<256, 256, 0, stream>>>(y_hist, W_ih, b_ih, b_hh, Wp, hs, hd, cbuf, t);
    }
    // T even -> final h in hb0
    fc_kernel<<<BB, 256, 0, stream>>>(hb0, W_fc, b_fc, out);
}